// Round 1
// baseline (5199.165 us; speedup 1.0000x reference)
//
#include <hip/hip_runtime.h>
#include <cmath>

namespace {

constexpr int B = 16, C = 3, H = 768, W = 768;
constexpr int HW = H * W;
constexpr int BC = B * C;
constexpr int NDROPS = 10;
constexpr int KS[NDROPS] = {23, 37, 13, 23, 13, 33, 25, 27, 15, 21};
constexpr float BLUR_R[NDROPS] = {11.3535f, 17.9381f, 5.7966f, 10.8586f, 5.5301f,
                                  15.9075f, 12.3225f, 13.4871f, 6.6639f, 9.5413f};
constexpr int MAXK = 37;

struct TapW {
    float w[MAXK];
};

}  // namespace

// ---------------------------------------------------------------------------
// Mask generation: all 10 drop masks at once. masks[j][y][x].
// mask = clip(exp(-(d^1.8) + 1e-10), 0, 1),
// d = (y-y0)^2/hr^2 + (x-x0)^2/wr^2, hr = 0.8*wr.
// ---------------------------------------------------------------------------
__global__ void mask_kernel(const float* __restrict__ pos,
                            const float* __restrict__ rad,
                            float* __restrict__ masks) {
    int idx = blockIdx.x * blockDim.x + threadIdx.x;
    if (idx >= HW) return;
    int y = idx / W;
    int x = idx - y * W;
    float fy = (float)y;
    float fx = (float)x;
#pragma unroll
    for (int j = 0; j < NDROPS; ++j) {
        float px = fminf(fmaxf(pos[2 * j + 0], -1.f), 1.f);
        float py = fminf(fmaxf(pos[2 * j + 1], -1.f), 1.f);
        float wr = fminf(fmaxf(rad[j], 60.f), 80.f);
        float x0 = (px + 1.f) * 0.5f * (float)W;
        float y0 = (py + 1.f) * 0.5f * (float)H;
        float hr = wr * 0.8f;
        float dy = fy - y0;
        float dx = fx - x0;
        float d = dy * dy / (hr * hr) + dx * dx / (wr * wr);
        float m = expf(-powf(d, 1.8f) + 1e-10f);
        m = fminf(fmaxf(m, 0.f), 1.f);
        masks[j * HW + idx] = m;
    }
}

// ---------------------------------------------------------------------------
// Vertical blur of (src * mask), reflect padding. dst = tmp.
// ---------------------------------------------------------------------------
template <int K>
__global__ void blurV(const float* __restrict__ src,
                      const float* __restrict__ mask,
                      float* __restrict__ dst, TapW tw) {
    constexpr int P = K / 2;
    int x = blockIdx.x * blockDim.x + threadIdx.x;  // 0..W-1 (grid exact)
    int y = blockIdx.y;
    int bc = blockIdx.z;
    const float* s = src + (size_t)bc * HW;
    float sum = 0.f;
#pragma unroll
    for (int t = 0; t < K; ++t) {
        int ry = y + t - P;
        ry = (ry < 0) ? -ry : ((ry >= H) ? 2 * H - 2 - ry : ry);
        int off = ry * W + x;
        sum += tw.w[t] * s[off] * mask[off];
    }
    dst[(size_t)bc * HW + y * W + x] = sum;
}

// ---------------------------------------------------------------------------
// Horizontal blur of tmp (reflect padding) + composite:
// out = blur * mask + prev * (1 - mask).  In-place safe (own-pixel RMW).
// ---------------------------------------------------------------------------
template <int K>
__global__ void blurH(const float* __restrict__ tmp,
                      const float* __restrict__ mask,
                      const float* __restrict__ prev,
                      float* __restrict__ out, TapW tw) {
    constexpr int P = K / 2;
    int x = blockIdx.x * blockDim.x + threadIdx.x;
    int y = blockIdx.y;
    int bc = blockIdx.z;
    const float* trow = tmp + (size_t)bc * HW + (size_t)y * W;
    float sum = 0.f;
#pragma unroll
    for (int t = 0; t < K; ++t) {
        int rx = x + t - P;
        rx = (rx < 0) ? -rx : ((rx >= W) ? 2 * W - 2 - rx : rx);
        sum += tw.w[t] * trow[rx];
    }
    float m = mask[y * W + x];
    size_t idx = (size_t)bc * HW + (size_t)y * W + x;
    out[idx] = sum * m + prev[idx] * (1.f - m);
}

// ---------------------------------------------------------------------------
// Host-side helpers
// ---------------------------------------------------------------------------
static void make_weights(int j, TapW& tw) {
    int K = KS[j];
    float sigma = BLUR_R[j];
    float half = (K - 1) * 0.5f;
    float sum = 0.f;
    for (int i = 0; i < K; ++i) {
        float xx = -half + (float)i;
        float v = xx / sigma;
        float p = expf(-0.5f * v * v);
        tw.w[i] = p;
        sum += p;
    }
    for (int i = 0; i < K; ++i) tw.w[i] /= sum;
    for (int i = K; i < MAXK; ++i) tw.w[i] = 0.f;
}

template <int K>
static void launch_pair(dim3 grid, hipStream_t stream, const float* src,
                        const float* mask, float* tmp, float* out,
                        const TapW& tw) {
    blurV<K><<<grid, 256, 0, stream>>>(src, mask, tmp, tw);
    blurH<K><<<grid, 256, 0, stream>>>(tmp, mask, src, out, tw);
}

static void launch_drop(int K, dim3 grid, hipStream_t stream, const float* src,
                        const float* mask, float* tmp, float* out,
                        const TapW& tw) {
    switch (K) {
        case 13: launch_pair<13>(grid, stream, src, mask, tmp, out, tw); break;
        case 15: launch_pair<15>(grid, stream, src, mask, tmp, out, tw); break;
        case 21: launch_pair<21>(grid, stream, src, mask, tmp, out, tw); break;
        case 23: launch_pair<23>(grid, stream, src, mask, tmp, out, tw); break;
        case 25: launch_pair<25>(grid, stream, src, mask, tmp, out, tw); break;
        case 27: launch_pair<27>(grid, stream, src, mask, tmp, out, tw); break;
        case 33: launch_pair<33>(grid, stream, src, mask, tmp, out, tw); break;
        case 37: launch_pair<37>(grid, stream, src, mask, tmp, out, tw); break;
    }
}

extern "C" void kernel_launch(void* const* d_in, const int* in_sizes, int n_in,
                              void* d_out, int out_size, void* d_ws,
                              size_t ws_size, hipStream_t stream) {
    const float* img = (const float*)d_in[0];
    const float* pos = (const float*)d_in[1];
    const float* rad = (const float*)d_in[2];
    float* out = (float*)d_out;

    // Workspace layout: [masks: 10*HW floats][tmp: B*C*HW floats] ~= 137 MB
    float* masks = (float*)d_ws;
    float* tmp = masks + (size_t)NDROPS * HW;

    mask_kernel<<<(HW + 255) / 256, 256, 0, stream>>>(pos, rad, masks);

    dim3 grid(W / 256, H, BC);  // 3 x 768 x 48 blocks of 256 threads
    for (int j = 0; j < NDROPS; ++j) {
        TapW tw;
        make_weights(j, tw);
        const float* src = (j == 0) ? img : out;  // drop 0 reads img directly
        launch_drop(KS[j], grid, stream, src, masks + (size_t)j * HW, tmp, out, tw);
    }
}

// Round 2
// 959.590 us; speedup vs baseline: 5.4181x; 5.4181x over previous
//
#include <hip/hip_runtime.h>
#include <cmath>

namespace {

constexpr int B = 16, C = 3, H = 768, W = 768;
constexpr int HW = H * W;
constexpr int BC = B * C;
constexpr int NDROPS = 10;
constexpr int KS[NDROPS] = {23, 37, 13, 23, 13, 33, 25, 27, 15, 21};
constexpr float BLUR_R[NDROPS] = {11.3535f, 17.9381f, 5.7966f, 10.8586f, 5.5301f,
                                  15.9075f, 12.3225f, 13.4871f, 6.6639f, 9.5413f};
constexpr int MAXK = 37;
constexpr int MAXP = MAXK / 2;  // 18

// mask < ~1e-7 outside d > SFAC^2 = 4.71  (d^1.8 > 16.2, exp -> <1e-7)
constexpr float SFAC = 2.17f;
// worst case: wr<=80 -> 2*2.17*80 = 347.2 px wide; hr<=64 -> 277.8 px tall
constexpr int BOXW = 384;              // 6 x 64
constexpr int BOXH = 288;              // 72 x 4
constexpr int VW = 448;                // 7 x 64 >= BOXW + 2*MAXP = 420

struct TapW {
    float w[MAXK];
};

}  // namespace

// ---------------------------------------------------------------------------
// Box origin from device-resident pos/rad (uniform across all threads).
// ---------------------------------------------------------------------------
__device__ inline void drop_box(const float* __restrict__ pos,
                                const float* __restrict__ rad, int j,
                                int& bx0, int& by0) {
    float px = fminf(fmaxf(pos[2 * j + 0], -1.f), 1.f);
    float py = fminf(fmaxf(pos[2 * j + 1], -1.f), 1.f);
    float wr = fminf(fmaxf(rad[j], 60.f), 80.f);
    float x0 = (px + 1.f) * 0.5f * (float)W;
    float y0 = (py + 1.f) * 0.5f * (float)H;
    float hr = wr * 0.8f;
    bx0 = max(0, (int)floorf(x0 - SFAC * wr));
    by0 = max(0, (int)floorf(y0 - SFAC * hr));
}

// ---------------------------------------------------------------------------
// Full-plane masks for all 10 drops (cheap; keeps reflect/halo reads safe).
// ---------------------------------------------------------------------------
__global__ void mask_kernel(const float* __restrict__ pos,
                            const float* __restrict__ rad,
                            float* __restrict__ masks) {
    int idx = blockIdx.x * blockDim.x + threadIdx.x;
    if (idx >= HW) return;
    int y = idx / W;
    int x = idx - y * W;
    float fy = (float)y;
    float fx = (float)x;
#pragma unroll
    for (int j = 0; j < NDROPS; ++j) {
        float px = fminf(fmaxf(pos[2 * j + 0], -1.f), 1.f);
        float py = fminf(fmaxf(pos[2 * j + 1], -1.f), 1.f);
        float wr = fminf(fmaxf(rad[j], 60.f), 80.f);
        float x0 = (px + 1.f) * 0.5f * (float)W;
        float y0 = (py + 1.f) * 0.5f * (float)H;
        float hr = wr * 0.8f;
        float dy = fy - y0;
        float dx = fx - x0;
        float d = dy * dy / (hr * hr) + dx * dx / (wr * wr);
        float m = expf(-powf(d, 1.8f) + 1e-10f);
        m = fminf(fmaxf(m, 0.f), 1.f);
        masks[j * HW + idx] = m;
    }
}

// ---------------------------------------------------------------------------
// out = img (vectorized full-image copy; everything outside drop boxes
// stays exactly img / previous state).
// ---------------------------------------------------------------------------
__global__ void copy_kernel(const float4* __restrict__ src,
                            float4* __restrict__ dst, int n) {
    int i = blockIdx.x * blockDim.x + threadIdx.x;
    if (i < n) dst[i] = src[i];
}

// ---------------------------------------------------------------------------
// Vertical blur of (out * mask), box-restricted, reflect padding.
// Writes vtmp[bc][y - by0][xi], xi spans [bx0-P, bx0-P+VW).
// ---------------------------------------------------------------------------
template <int K>
__global__ void blurV_box(const float* __restrict__ out,
                          const float* __restrict__ mask,
                          float* __restrict__ vtmp,
                          const float* __restrict__ pos,
                          const float* __restrict__ rad, int j, TapW tw) {
    constexpr int P = K / 2;
    int bx0, by0;
    drop_box(pos, rad, j, bx0, by0);
    int xi = blockIdx.x * 64 + threadIdx.x;              // 0..VW-1
    int y = by0 + blockIdx.y * 4 + threadIdx.y;          // by0..by0+BOXH-1
    int bc = blockIdx.z;
    int x = bx0 - P + xi;
    if (x < 0 || x >= W || y >= H) return;
    const float* s = out + (size_t)bc * HW;
    float sum = 0.f;
#pragma unroll
    for (int t = 0; t < K; ++t) {
        int ry = y + t - P;
        ry = (ry < 0) ? -ry : ((ry >= H) ? 2 * H - 2 - ry : ry);
        int off = ry * W + x;
        sum += tw.w[t] * s[off] * mask[off];
    }
    vtmp[((size_t)bc * BOXH + (y - by0)) * VW + xi] = sum;
}

// ---------------------------------------------------------------------------
// Horizontal blur of vtmp + composite, box-restricted, in-place on out.
// ---------------------------------------------------------------------------
template <int K>
__global__ void blurH_box(const float* __restrict__ vtmp,
                          const float* __restrict__ mask,
                          float* __restrict__ out,
                          const float* __restrict__ pos,
                          const float* __restrict__ rad, int j, TapW tw) {
    constexpr int P = K / 2;
    int bx0, by0;
    drop_box(pos, rad, j, bx0, by0);
    int x = bx0 + blockIdx.x * 64 + threadIdx.x;         // box x
    int y = by0 + blockIdx.y * 4 + threadIdx.y;          // box y
    int bc = blockIdx.z;
    if (x >= W || y >= H) return;
    const float* vrow = vtmp + ((size_t)bc * BOXH + (y - by0)) * VW;
    float sum = 0.f;
#pragma unroll
    for (int t = 0; t < K; ++t) {
        int rx = x + t - P;
        rx = (rx < 0) ? -rx : ((rx >= W) ? 2 * W - 2 - rx : rx);
        sum += tw.w[t] * vrow[rx - (bx0 - P)];
    }
    float m = mask[y * W + x];
    size_t idx = (size_t)bc * HW + (size_t)y * W + x;
    out[idx] = sum * m + out[idx] * (1.f - m);
}

// ---------------------------------------------------------------------------
// Host-side helpers
// ---------------------------------------------------------------------------
static void make_weights(int j, TapW& tw) {
    int K = KS[j];
    float sigma = BLUR_R[j];
    float half = (K - 1) * 0.5f;
    float sum = 0.f;
    for (int i = 0; i < K; ++i) {
        float xx = -half + (float)i;
        float v = xx / sigma;
        float p = expf(-0.5f * v * v);
        tw.w[i] = p;
        sum += p;
    }
    for (int i = 0; i < K; ++i) tw.w[i] /= sum;
    for (int i = K; i < MAXK; ++i) tw.w[i] = 0.f;
}

template <int K>
static void launch_pair(hipStream_t stream, const float* mask, float* vtmp,
                        float* out, const float* pos, const float* rad, int j,
                        const TapW& tw) {
    dim3 blk(64, 4, 1);
    dim3 gV(VW / 64, BOXH / 4, BC);    // 7 x 72 x 48
    dim3 gH(BOXW / 64, BOXH / 4, BC);  // 6 x 72 x 48
    blurV_box<K><<<gV, blk, 0, stream>>>(out, mask, vtmp, pos, rad, j, tw);
    blurH_box<K><<<gH, blk, 0, stream>>>(vtmp, mask, out, pos, rad, j, tw);
}

static void launch_drop(int K, hipStream_t stream, const float* mask,
                        float* vtmp, float* out, const float* pos,
                        const float* rad, int j, const TapW& tw) {
    switch (K) {
        case 13: launch_pair<13>(stream, mask, vtmp, out, pos, rad, j, tw); break;
        case 15: launch_pair<15>(stream, mask, vtmp, out, pos, rad, j, tw); break;
        case 21: launch_pair<21>(stream, mask, vtmp, out, pos, rad, j, tw); break;
        case 23: launch_pair<23>(stream, mask, vtmp, out, pos, rad, j, tw); break;
        case 25: launch_pair<25>(stream, mask, vtmp, out, pos, rad, j, tw); break;
        case 27: launch_pair<27>(stream, mask, vtmp, out, pos, rad, j, tw); break;
        case 33: launch_pair<33>(stream, mask, vtmp, out, pos, rad, j, tw); break;
        case 37: launch_pair<37>(stream, mask, vtmp, out, pos, rad, j, tw); break;
    }
}

extern "C" void kernel_launch(void* const* d_in, const int* in_sizes, int n_in,
                              void* d_out, int out_size, void* d_ws,
                              size_t ws_size, hipStream_t stream) {
    const float* img = (const float*)d_in[0];
    const float* pos = (const float*)d_in[1];
    const float* rad = (const float*)d_in[2];
    float* out = (float*)d_out;

    // ws layout: [masks: 10*HW f32 = 23.6MB][vtmp: BC*BOXH*VW f32 = 24.8MB]
    float* masks = (float*)d_ws;
    float* vtmp = masks + (size_t)NDROPS * HW;

    mask_kernel<<<(HW + 255) / 256, 256, 0, stream>>>(pos, rad, masks);
    copy_kernel<<<(BC * HW / 4 + 255) / 256, 256, 0, stream>>>(
        (const float4*)img, (float4*)out, BC * HW / 4);

    for (int j = 0; j < NDROPS; ++j) {
        TapW tw;
        make_weights(j, tw);
        launch_drop(KS[j], stream, masks + (size_t)j * HW, vtmp, out, pos, rad,
                    j, tw);
    }
}

// Round 3
// 640.203 us; speedup vs baseline: 8.1211x; 1.4989x over previous
//
#include <hip/hip_runtime.h>
#include <cmath>

namespace {

constexpr int B = 16, C = 3, H = 768, W = 768;
constexpr int HW = H * W;
constexpr int BC = B * C;
constexpr int NDROPS = 10;
constexpr int KS[NDROPS] = {23, 37, 13, 23, 13, 33, 25, 27, 15, 21};
constexpr float BLUR_R[NDROPS] = {11.3535f, 17.9381f, 5.7966f, 10.8586f, 5.5301f,
                                  15.9075f, 12.3225f, 13.4871f, 6.6639f, 9.5413f};
constexpr int MAXK = 37;
constexpr int MAXP = MAXK / 2;  // 18

// mask < ~8.6e-8 outside d > SFAC^2 (d^1.8 > 16.2). Outside the box the
// composite is identical to prev to within 1e-7 (<< harness tolerance).
constexpr float SFAC = 2.17f;
constexpr int BOXW = 384;  // >= 2*2.17*80 = 348
constexpr int BOXH = 288;  // >= 2*2.17*64 = 278
constexpr int VW = 448;    // 7*64 >= BOXW + 2*MAXP = 420 (virtual-x extent)
constexpr int YT = 16;     // output rows per fusedV tile

struct TapW {
    float w[MAXK];
};

}  // namespace

__device__ inline int refl(int v, int n) {
    return v < 0 ? -v : (v >= n ? 2 * n - 2 - v : v);
}

__device__ inline void drop_box(const float* __restrict__ pos,
                                const float* __restrict__ rad, int j,
                                int& bx0, int& by0) {
    float px = fminf(fmaxf(pos[2 * j + 0], -1.f), 1.f);
    float py = fminf(fmaxf(pos[2 * j + 1], -1.f), 1.f);
    float wr = fminf(fmaxf(rad[j], 60.f), 80.f);
    float x0 = (px + 1.f) * 0.5f * (float)W;
    float y0 = (py + 1.f) * 0.5f * (float)H;
    float hr = wr * 0.8f;
    bx0 = max(0, (int)floorf(x0 - SFAC * wr));
    by0 = max(0, (int)floorf(y0 - SFAC * hr));
}

// ---------------------------------------------------------------------------
// Full-plane masks for all 10 drops (reflected halo reads stay exact).
// ---------------------------------------------------------------------------
__global__ void mask_kernel(const float* __restrict__ pos,
                            const float* __restrict__ rad,
                            float* __restrict__ masks) {
    int idx = blockIdx.x * blockDim.x + threadIdx.x;
    if (idx >= HW) return;
    int y = idx / W;
    int x = idx - y * W;
    float fy = (float)y;
    float fx = (float)x;
#pragma unroll
    for (int j = 0; j < NDROPS; ++j) {
        float px = fminf(fmaxf(pos[2 * j + 0], -1.f), 1.f);
        float py = fminf(fmaxf(pos[2 * j + 1], -1.f), 1.f);
        float wr = fminf(fmaxf(rad[j], 60.f), 80.f);
        float x0 = (px + 1.f) * 0.5f * (float)W;
        float y0 = (py + 1.f) * 0.5f * (float)H;
        float hr = wr * 0.8f;
        float dy = fy - y0;
        float dx = fx - x0;
        float d = dy * dy / (hr * hr) + dx * dx / (wr * wr);
        float m = expf(-powf(d, 1.8f) + 1e-10f);
        m = fminf(fmaxf(m, 0.f), 1.f);
        masks[j * HW + idx] = m;
    }
}

__global__ void copy_kernel(const float4* __restrict__ src,
                            float4* __restrict__ dst, int n) {
    int i = blockIdx.x * blockDim.x + threadIdx.x;
    if (i < n) dst[i] = src[i];
}

// ---------------------------------------------------------------------------
// Fused product + vertical blur, LDS-tiled.
// Output column c of vtmp holds the V-blur of (out*mask) at the REFLECTED
// image column refl(bx0 - MAXP + c): blurH2 then needs no reflect at all.
// Reflect + mask product are computed once per pixel (phase A), taps are
// 1 ds_read + 4 FMA per 4 outputs (phase B, 4-way y-coarsening).
// ---------------------------------------------------------------------------
template <int K>
__global__ __launch_bounds__(256) void fusedV(
    const float* __restrict__ out, const float* __restrict__ mask,
    float* __restrict__ vtmp, const float* __restrict__ pos,
    const float* __restrict__ rad, int j, TapW tw) {
    constexpr int P = K / 2;
    constexpr int TR = YT + K - 1;  // product tile rows (<= 52)
    __shared__ float prod[TR][64];

    int bx0, by0;
    drop_box(pos, rad, j, bx0, by0);
    int c = blockIdx.x * 64 + threadIdx.x;  // [0, VW)
    int yi0 = blockIdx.y * YT;              // [0, BOXH)
    int bc = blockIdx.z;
    int rx = refl(bx0 - MAXP + c, W);  // per-thread, once
    const float* op = out + (size_t)bc * HW;

    // Phase A: product tile (reflect once per pixel)
    for (int lr = threadIdx.y; lr < TR; lr += 4) {
        int ry = refl(by0 + yi0 - P + lr, H);
        int off = ry * W + rx;
        prod[lr][threadIdx.x] = op[off] * mask[off];
    }
    __syncthreads();

    // Phase B: vertical blur, 4 outputs per thread, sliding LDS reads
    float acc[4] = {0.f, 0.f, 0.f, 0.f};
    int base = threadIdx.y * 4;  // output rows base..base+3 within tile
#pragma unroll
    for (int t = 0; t < K + 3; ++t) {
        float v = prod[base + t][threadIdx.x];
#pragma unroll
        for (int o = 0; o < 4; ++o) {
            int ti = t - o;
            if (ti >= 0 && ti < K) acc[o] += tw.w[ti] * v;
        }
    }
    float* vp = vtmp + ((size_t)bc * BOXH + yi0 + base) * VW + c;
#pragma unroll
    for (int o = 0; o < 4; ++o) vp[(size_t)o * VW] = acc[o];
}

// ---------------------------------------------------------------------------
// Horizontal blur of vtmp (contiguous, immediate-offset taps) + composite.
// In-place own-pixel RMW on out (race-free).
// ---------------------------------------------------------------------------
template <int K>
__global__ __launch_bounds__(256) void blurH2(
    const float* __restrict__ vtmp, const float* __restrict__ mask,
    float* __restrict__ out, const float* __restrict__ pos,
    const float* __restrict__ rad, int j, TapW tw) {
    constexpr int P = K / 2;
    constexpr int OFF = MAXP - P;
    int bx0, by0;
    drop_box(pos, rad, j, bx0, by0);
    int c = blockIdx.x * 64 + threadIdx.x;  // [0, BOXW)
    int yi = blockIdx.y * 4 + threadIdx.y;  // [0, BOXH)
    int bc = blockIdx.z;
    int x = bx0 + c;
    int y = by0 + yi;
    if (x >= W || y >= H) return;
    const float* vrow = vtmp + ((size_t)bc * BOXH + yi) * VW + (c + OFF);
    float sum = 0.f;
#pragma unroll
    for (int t = 0; t < K; ++t) sum += tw.w[t] * vrow[t];
    float m = mask[y * W + x];
    size_t idx = (size_t)bc * HW + (size_t)y * W + x;
    out[idx] = sum * m + out[idx] * (1.f - m);
}

// ---------------------------------------------------------------------------
// Host-side helpers
// ---------------------------------------------------------------------------
static void make_weights(int j, TapW& tw) {
    int K = KS[j];
    float sigma = BLUR_R[j];
    float half = (K - 1) * 0.5f;
    float sum = 0.f;
    for (int i = 0; i < K; ++i) {
        float xx = -half + (float)i;
        float v = xx / sigma;
        float p = expf(-0.5f * v * v);
        tw.w[i] = p;
        sum += p;
    }
    for (int i = 0; i < K; ++i) tw.w[i] /= sum;
    for (int i = K; i < MAXK; ++i) tw.w[i] = 0.f;
}

template <int K>
static void launch_pair(hipStream_t stream, const float* mask, float* vtmp,
                        float* out, const float* pos, const float* rad, int j,
                        const TapW& tw) {
    dim3 blk(64, 4, 1);
    dim3 gV(VW / 64, BOXH / YT, BC);  // 7 x 18 x 48
    dim3 gH(BOXW / 64, BOXH / 4, BC); // 6 x 72 x 48
    fusedV<K><<<gV, blk, 0, stream>>>(out, mask, vtmp, pos, rad, j, tw);
    blurH2<K><<<gH, blk, 0, stream>>>(vtmp, mask, out, pos, rad, j, tw);
}

static void launch_drop(int K, hipStream_t stream, const float* mask,
                        float* vtmp, float* out, const float* pos,
                        const float* rad, int j, const TapW& tw) {
    switch (K) {
        case 13: launch_pair<13>(stream, mask, vtmp, out, pos, rad, j, tw); break;
        case 15: launch_pair<15>(stream, mask, vtmp, out, pos, rad, j, tw); break;
        case 21: launch_pair<21>(stream, mask, vtmp, out, pos, rad, j, tw); break;
        case 23: launch_pair<23>(stream, mask, vtmp, out, pos, rad, j, tw); break;
        case 25: launch_pair<25>(stream, mask, vtmp, out, pos, rad, j, tw); break;
        case 27: launch_pair<27>(stream, mask, vtmp, out, pos, rad, j, tw); break;
        case 33: launch_pair<33>(stream, mask, vtmp, out, pos, rad, j, tw); break;
        case 37: launch_pair<37>(stream, mask, vtmp, out, pos, rad, j, tw); break;
    }
}

extern "C" void kernel_launch(void* const* d_in, const int* in_sizes, int n_in,
                              void* d_out, int out_size, void* d_ws,
                              size_t ws_size, hipStream_t stream) {
    const float* img = (const float*)d_in[0];
    const float* pos = (const float*)d_in[1];
    const float* rad = (const float*)d_in[2];
    float* out = (float*)d_out;

    // ws layout: [masks: 10*HW f32 = 23.6MB][vtmp: BC*BOXH*VW f32 = 24.8MB]
    float* masks = (float*)d_ws;
    float* vtmp = masks + (size_t)NDROPS * HW;

    mask_kernel<<<(HW + 255) / 256, 256, 0, stream>>>(pos, rad, masks);
    copy_kernel<<<(BC * HW / 4 + 255) / 256, 256, 0, stream>>>(
        (const float4*)img, (float4*)out, BC * HW / 4);

    for (int j = 0; j < NDROPS; ++j) {
        TapW tw;
        make_weights(j, tw);
        launch_drop(KS[j], stream, masks + (size_t)j * HW, vtmp, out, pos, rad,
                    j, tw);
    }
}